// Round 2
// baseline (312.245 us; speedup 1.0000x reference)
//
#include <hip/hip_runtime.h>
#include <hip/hip_bf16.h>

// GNN EdgeConv, 3 layers. fp32 in/out; GEMM in bf16 (MFMA) w/ fp32 accumulate.
// nodes=4096, C=256, E=65536, HID=256. Output [4096][1024] = [x0|x1|x2|x3] fp32.

#define NODES 4096
#define EDGES 65536
#define OSTR 1024   // out row stride (fp32 elems)

typedef __attribute__((ext_vector_type(8))) short bf16x8;
typedef __attribute__((ext_vector_type(4))) float f32x4;

__device__ __forceinline__ unsigned short f2bf(float f) {
    unsigned int x = __float_as_uint(f);
    return (unsigned short)((x + 0x7fff + ((x >> 16) & 1)) >> 16); // RNE
}

// Copy x0 (fp32) into out cols [0,256), make bf16 mirror, zero scatter buffer.
__global__ __launch_bounds__(256) void k_init(const float* __restrict__ x0,
                                              float* __restrict__ out,
                                              unsigned short* __restrict__ xbuf,
                                              float* __restrict__ seg) {
    int idx = blockIdx.x * 256 + threadIdx.x;  // 0 .. 4096*256-1
    int node = idx >> 8, c = idx & 255;
    float v = x0[idx];
    out[node * OSTR + c] = v;
    xbuf[idx] = f2bf(v);
    seg[idx] = 0.0f;
}

// W' = [Wa | Wb - Wa] (fp32 math, one bf16 rounding) so A-staging is a pure
// gather of [x_j | x_i]:  [xj-xi | xi] @ [Wa|Wb]^T == [xj | xi] @ [Wa|Wb-Wa]^T.
__global__ __launch_bounds__(256) void k_wprep(const float* __restrict__ W,
                                               unsigned short* __restrict__ Wp) {
    int idx = blockIdx.x * 256 + threadIdx.x;  // 0 .. 256*512-1
    int k = idx & 511;
    float v = W[idx];
    if (k >= 256) v -= W[idx - 256];
    Wp[idx] = f2bf(v);
}

// One block: 32 edges x 256 out channels, K=512. 4 waves, each 32(m)x64(n).
__global__ __launch_bounds__(256) void k_gemm(const unsigned short* __restrict__ xbuf, // [4096][256] bf16
                                              const short* __restrict__ Wp,            // [256][512] bf16
                                              const float* __restrict__ bias,          // [256] fp32
                                              const int* __restrict__ srcIdx,
                                              const int* __restrict__ dstIdx,
                                              float* __restrict__ seg) {
    // 520 = 512 + 8 pad: row stride 260 dwords == 4 mod 32 -> only 2-way LDS
    // conflicts on ds_read_b128 (free per m136). Row stride 1040 B is 16B-aligned.
    __shared__ __align__(16) short Alds[32 * 520];
    __shared__ int dstS[32];

    const int t = threadIdx.x;
    const int e0 = blockIdx.x * 32;

    // ---- stage A = [x[src] | x[dst]] : 32 rows x 512 bf16 ----
    {
        int el = t >> 3, sub = t & 7;            // 8 threads per edge row
        int sRow = srcIdx[e0 + el];
        int dRow = dstIdx[e0 + el];
        const int4* ps = (const int4*)(xbuf + (size_t)sRow * 256);
        const int4* pd = (const int4*)(xbuf + (size_t)dRow * 256);
        short* arow = &Alds[el * 520];
#pragma unroll
        for (int j = 0; j < 4; ++j) {
            int c = sub + 8 * j;                 // 16B chunk index, 0..31
            *(int4*)(arow + c * 8) = ps[c];          // k in [0,256)  = x_j
            *(int4*)(arow + 256 + c * 8) = pd[c];    // k in [256,512) = x_i
        }
        if (t < 32) dstS[t] = dstIdx[e0 + t];
    }
    __syncthreads();

    const int wave = t >> 6, lane = t & 63;
    const int lm = lane & 15, kq = lane >> 4;
    const int nb = wave * 64;

    f32x4 acc[2][4];
#pragma unroll
    for (int mt = 0; mt < 2; ++mt)
#pragma unroll
        for (int nt = 0; nt < 4; ++nt) acc[mt][nt] = (f32x4){0.f, 0.f, 0.f, 0.f};

    // A-frag: A[m=lane&15][k=(lane>>4)*8+j] (m120-verified layout)
    const short* a0p = &Alds[lm * 520 + kq * 8];
    const short* a1p = a0p + 16 * 520;
    // B-frag: B[k=(lane>>4)*8+j][n=lane&15]; B[k][n] = W'[n][k] -> read W' row n
    const short* bp = Wp + (nb + lm) * 512 + kq * 8;

#pragma unroll
    for (int ks = 0; ks < 16; ++ks) {
        const int ko = ks * 32;
        bf16x8 a0 = *(const bf16x8*)(a0p + ko);
        bf16x8 a1 = *(const bf16x8*)(a1p + ko);
        bf16x8 b0 = *(const bf16x8*)(bp + ko);
        bf16x8 b1 = *(const bf16x8*)(bp + 16 * 512 + ko);
        bf16x8 b2 = *(const bf16x8*)(bp + 32 * 512 + ko);
        bf16x8 b3 = *(const bf16x8*)(bp + 48 * 512 + ko);
        acc[0][0] = __builtin_amdgcn_mfma_f32_16x16x32_bf16(a0, b0, acc[0][0], 0, 0, 0);
        acc[0][1] = __builtin_amdgcn_mfma_f32_16x16x32_bf16(a0, b1, acc[0][1], 0, 0, 0);
        acc[0][2] = __builtin_amdgcn_mfma_f32_16x16x32_bf16(a0, b2, acc[0][2], 0, 0, 0);
        acc[0][3] = __builtin_amdgcn_mfma_f32_16x16x32_bf16(a0, b3, acc[0][3], 0, 0, 0);
        acc[1][0] = __builtin_amdgcn_mfma_f32_16x16x32_bf16(a1, b0, acc[1][0], 0, 0, 0);
        acc[1][1] = __builtin_amdgcn_mfma_f32_16x16x32_bf16(a1, b1, acc[1][1], 0, 0, 0);
        acc[1][2] = __builtin_amdgcn_mfma_f32_16x16x32_bf16(a1, b2, acc[1][2], 0, 0, 0);
        acc[1][3] = __builtin_amdgcn_mfma_f32_16x16x32_bf16(a1, b3, acc[1][3], 0, 0, 0);
    }

    // ---- epilogue: bias (fp32), relu-filter, atomicMax scatter onto dst ----
    // C/D layout: col(n) = lane&15, row(m) = (lane>>4)*4 + reg  (m89/m91)
    // relu∘max commute: max_e relu(v) = max(0, max_e v); seg starts at 0 and
    // v<=0 lanes skip the atomic. uint-compare == float-compare for v>=0.
#pragma unroll
    for (int nt = 0; nt < 4; ++nt) {
        int ncol = nb + nt * 16 + lm;
        float bc = bias[ncol];
#pragma unroll
        for (int mt = 0; mt < 2; ++mt) {
#pragma unroll
            for (int p = 0; p < 4; ++p) {
                int erow = mt * 16 + kq * 4 + p;
                float v = acc[mt][nt][p] + bc;
                if (v > 0.0f) {
                    atomicMax((unsigned int*)(seg + (size_t)dstS[erow] * 256 + ncol),
                              __float_as_uint(v));
                }
            }
        }
    }
}

// seg (fp32, >=0) -> out cols [ooff, ooff+256) fp32 + bf16 mirror; re-zero seg.
__global__ __launch_bounds__(256) void k_finish(float* __restrict__ seg,
                                                float* __restrict__ out,
                                                unsigned short* __restrict__ xbuf,
                                                int ooff) {
    int idx = blockIdx.x * 256 + threadIdx.x;
    int node = idx >> 8, c = idx & 255;
    float v = seg[idx];
    out[node * OSTR + ooff + c] = v;
    xbuf[idx] = f2bf(v);
    seg[idx] = 0.0f;
}

extern "C" void kernel_launch(void* const* d_in, const int* in_sizes, int n_in,
                              void* d_out, int out_size, void* d_ws, size_t ws_size,
                              hipStream_t stream) {
    const float* x0 = (const float*)d_in[0];
    const int* ei = (const int*)d_in[1];
    const int* srcIdx = ei;          // edge_index[0] = src
    const int* dstIdx = ei + EDGES;  // edge_index[1] = dst

    float* out = (float*)d_out;
    // ws layout: seg fp32 [4096*256] (4 MB) | xbuf bf16 [4096*256] (2 MB) | Wp 3x[256*512] bf16 (0.75 MB)
    float* seg = (float*)d_ws;
    unsigned short* xbuf = (unsigned short*)((char*)d_ws + (size_t)NODES * 256 * 4);
    short* Wp = (short*)((char*)xbuf + (size_t)NODES * 256 * 2);

    k_init<<<NODES, 256, 0, stream>>>(x0, out, xbuf, seg);
    for (int l = 0; l < 3; ++l) {
        k_wprep<<<512, 256, 0, stream>>>((const float*)d_in[2 + 2 * l],
                                         (unsigned short*)(Wp + l * 131072));
    }
    for (int l = 0; l < 3; ++l) {
        k_gemm<<<EDGES / 32, 256, 0, stream>>>(xbuf, Wp + l * 131072,
                                               (const float*)d_in[3 + 2 * l],
                                               srcIdx, dstIdx, seg);
        k_finish<<<NODES, 256, 0, stream>>>(seg, out, xbuf, (l + 1) * 256);
    }
}

// Round 3
// 153.847 us; speedup vs baseline: 2.0296x; 2.0296x over previous
//
#include <hip/hip_runtime.h>
#include <hip/hip_bf16.h>

// GNN EdgeConv, 3 layers, fp32 in/out.
// Restructured: msg_e = relu(u[src]+w[dst]) with per-NODE GEMM
//   u = x@Wa^T, w = x@(Wb-Wa)^T + b   (16x fewer FLOPs than per-edge GEMM)
// and dst-sorted edges (counting sort) so scatter-max becomes per-node
// gather-max with ZERO atomics (round-2 counters: 65 MB HBM atomic writes
// per gemm dispatch was the bottleneck).

#define NODES 4096
#define EDGES 65536
#define OSTR 1024   // out row stride (fp32)

typedef __attribute__((ext_vector_type(8))) short bf16x8;
typedef __attribute__((ext_vector_type(4))) float f32x4;

__device__ __forceinline__ unsigned short f2bf(float f) {
    unsigned int x = __float_as_uint(f);
    return (unsigned short)((x + 0x7fff + ((x >> 16) & 1)) >> 16); // RNE
}

// ---- x0 -> out cols [0,256) ----
__global__ __launch_bounds__(256) void k_init(const float* __restrict__ x0,
                                              float* __restrict__ out) {
    int idx = blockIdx.x * 256 + threadIdx.x;
    int node = idx >> 8, c = idx & 255;
    out[node * OSTR + c] = x0[idx];
}

// ---- Wp[n][c] (bf16, [512][256]): n<256 -> Wa[n][c]; else (Wb-Wa)[n-256][c].
// One dispatch covers all 3 layers. W input layout [256][512] = [o][Wa|Wb].
__global__ __launch_bounds__(256) void k_wprep(const float* __restrict__ W0,
                                               const float* __restrict__ W1,
                                               const float* __restrict__ W2,
                                               short* __restrict__ Wp) {
    int layer = blockIdx.x >> 9;               // 512 blocks per layer
    int idx = (blockIdx.x & 511) * 256 + threadIdx.x;  // 0 .. 512*256-1
    const float* W = layer == 0 ? W0 : (layer == 1 ? W1 : W2);
    int n = idx >> 8, c = idx & 255;
    float v;
    if (n < 256) v = W[n * 512 + c];
    else         v = W[(n - 256) * 512 + 256 + c] - W[(n - 256) * 512 + c];
    Wp[layer * 131072 + idx] = (short)f2bf(v);
}

// ---- counting sort of edges by dst ----
__global__ __launch_bounds__(256) void k_zero(int* __restrict__ cnt) {
    cnt[blockIdx.x * 256 + threadIdx.x] = 0;
}
__global__ __launch_bounds__(256) void k_hist(const int* __restrict__ dst,
                                              int* __restrict__ cnt) {
    int e = blockIdx.x * 256 + threadIdx.x;
    atomicAdd(&cnt[dst[e]], 1);
}
// single block: exclusive scan of cnt[4096] -> offsets[4097]; re-zero cnt (cursor).
__global__ __launch_bounds__(256) void k_scan(int* __restrict__ cnt,
                                              int* __restrict__ offsets) {
    __shared__ int part[256];
    int t = threadIdx.x, base = t * 16;
    int loc[16], s = 0;
#pragma unroll
    for (int j = 0; j < 16; ++j) { loc[j] = cnt[base + j]; s += loc[j]; }
    part[t] = s;
    __syncthreads();
    for (int d = 1; d < 256; d <<= 1) {
        int v = (t >= d) ? part[t - d] : 0;
        __syncthreads();
        part[t] += v;
        __syncthreads();
    }
    int run = part[t] - s;  // exclusive prefix
#pragma unroll
    for (int j = 0; j < 16; ++j) { offsets[base + j] = run; run += loc[j]; cnt[base + j] = 0; }
    if (t == 255) offsets[4096] = run;
}
__global__ __launch_bounds__(256) void k_scatter(const int* __restrict__ src,
                                                 const int* __restrict__ dst,
                                                 const int* __restrict__ offsets,
                                                 int* __restrict__ cursor,
                                                 int* __restrict__ srcS) {
    int e = blockIdx.x * 256 + threadIdx.x;
    int d = dst[e];
    int p = offsets[d] + atomicAdd(&cursor[d], 1);
    srcS[p] = src[e];
}

// ---- node GEMM: UW[4096][512] = X(bf16) @ Wp^T (+bias on cols 256..511) ----
// X read from out cols [loff,loff+256) fp32, converted to bf16 during staging.
// Block: 32 rows x 256 cols; grid (128, 2). 4 waves, each 32(m)x64(n).
__global__ __launch_bounds__(256) void k_gemm(const float* __restrict__ X,   // out + loff, row stride 1024
                                              const short* __restrict__ Wp,  // [512][256] bf16
                                              const float* __restrict__ bias,
                                              float* __restrict__ UW) {
    // stride 264 shorts = 132 dwords == 4 mod 32 -> 2-way LDS read conflicts (free)
    __shared__ __align__(16) short Alds[32 * 264];

    const int t = threadIdx.x;
    const int m0 = blockIdx.x * 32;
    const int nhalf = blockIdx.y;

    // stage A: 32 rows x 256 k, fp32->bf16
    {
        int r = t >> 3, ch = t & 7;  // 8 threads/row, 32 cols each
        const float4* xr4 = (const float4*)(X + (size_t)(m0 + r) * OSTR + ch * 32);
        short* arow = &Alds[r * 264 + ch * 32];
#pragma unroll
        for (int jj = 0; jj < 4; ++jj) {
            float4 a = xr4[2 * jj], b = xr4[2 * jj + 1];
            int4 pk;
            unsigned short* u = (unsigned short*)&pk;
            u[0] = f2bf(a.x); u[1] = f2bf(a.y); u[2] = f2bf(a.z); u[3] = f2bf(a.w);
            u[4] = f2bf(b.x); u[5] = f2bf(b.y); u[6] = f2bf(b.z); u[7] = f2bf(b.w);
            *(int4*)(arow + jj * 8) = pk;
        }
    }
    __syncthreads();

    const int wave = t >> 6, lane = t & 63;
    const int lm = lane & 15, kq = lane >> 4;
    const int nb = nhalf * 256 + wave * 64;

    f32x4 acc[2][4];
#pragma unroll
    for (int mt = 0; mt < 2; ++mt)
#pragma unroll
        for (int nt = 0; nt < 4; ++nt) acc[mt][nt] = (f32x4){0.f, 0.f, 0.f, 0.f};

    const short* a0p = &Alds[lm * 264 + kq * 8];
    const short* a1p = a0p + 16 * 264;
    const short* bp = Wp + (size_t)(nb + lm) * 256 + kq * 8;

#pragma unroll
    for (int ks = 0; ks < 8; ++ks) {
        const int ko = ks * 32;
        bf16x8 a0 = *(const bf16x8*)(a0p + ko);
        bf16x8 a1 = *(const bf16x8*)(a1p + ko);
        bf16x8 b0 = *(const bf16x8*)(bp + ko);
        bf16x8 b1 = *(const bf16x8*)(bp + 16 * 256 + ko);
        bf16x8 b2 = *(const bf16x8*)(bp + 32 * 256 + ko);
        bf16x8 b3 = *(const bf16x8*)(bp + 48 * 256 + ko);
        acc[0][0] = __builtin_amdgcn_mfma_f32_16x16x32_bf16(a0, b0, acc[0][0], 0, 0, 0);
        acc[0][1] = __builtin_amdgcn_mfma_f32_16x16x32_bf16(a0, b1, acc[0][1], 0, 0, 0);
        acc[0][2] = __builtin_amdgcn_mfma_f32_16x16x32_bf16(a0, b2, acc[0][2], 0, 0, 0);
        acc[0][3] = __builtin_amdgcn_mfma_f32_16x16x32_bf16(a0, b3, acc[0][3], 0, 0, 0);
        acc[1][0] = __builtin_amdgcn_mfma_f32_16x16x32_bf16(a1, b0, acc[1][0], 0, 0, 0);
        acc[1][1] = __builtin_amdgcn_mfma_f32_16x16x32_bf16(a1, b1, acc[1][1], 0, 0, 0);
        acc[1][2] = __builtin_amdgcn_mfma_f32_16x16x32_bf16(a1, b2, acc[1][2], 0, 0, 0);
        acc[1][3] = __builtin_amdgcn_mfma_f32_16x16x32_bf16(a1, b3, acc[1][3], 0, 0, 0);
    }

    // epilogue: C/D layout col=lane&15, row=(lane>>4)*4+reg (m89/m91)
#pragma unroll
    for (int nt = 0; nt < 4; ++nt) {
        int ncol = nb + nt * 16 + lm;
        float bc = (nhalf == 1) ? bias[ncol - 256] : 0.0f;
#pragma unroll
        for (int mt = 0; mt < 2; ++mt) {
#pragma unroll
            for (int p = 0; p < 4; ++p) {
                int erow = mt * 16 + kq * 4 + p;
                UW[(size_t)(m0 + erow) * 512 + ncol] = acc[mt][nt][p] + bc;
            }
        }
    }
}

// ---- per-dst gather-max: out[i] = relu(max_{e in(i)} u[src] + w[i]); empty->0.
// 1 wave/node; 64 lanes x float4 = 256 channels. Zero atomics.
__global__ __launch_bounds__(64) void k_edge(const float* __restrict__ UW,
                                             const int* __restrict__ offsets,
                                             const int* __restrict__ srcS,
                                             float* __restrict__ out,
                                             int ooff) {
    const int i = blockIdx.x;
    const int l = threadIdx.x;  // 0..63
    const int beg = offsets[i], end = offsets[i + 1];

    const float NEG = -3.4e38f;
    float4 m = {NEG, NEG, NEG, NEG};
    int e = beg;
    for (; e + 4 <= end; e += 4) {
        int s0 = srcS[e], s1 = srcS[e + 1], s2 = srcS[e + 2], s3 = srcS[e + 3];
        float4 v0 = *(const float4*)(UW + (size_t)s0 * 512 + l * 4);
        float4 v1 = *(const float4*)(UW + (size_t)s1 * 512 + l * 4);
        float4 v2 = *(const float4*)(UW + (size_t)s2 * 512 + l * 4);
        float4 v3 = *(const float4*)(UW + (size_t)s3 * 512 + l * 4);
        m.x = fmaxf(fmaxf(fmaxf(m.x, v0.x), fmaxf(v1.x, v2.x)), v3.x);
        m.y = fmaxf(fmaxf(fmaxf(m.y, v0.y), fmaxf(v1.y, v2.y)), v3.y);
        m.z = fmaxf(fmaxf(fmaxf(m.z, v0.z), fmaxf(v1.z, v2.z)), v3.z);
        m.w = fmaxf(fmaxf(fmaxf(m.w, v0.w), fmaxf(v1.w, v2.w)), v3.w);
    }
    for (; e < end; ++e) {
        int s = srcS[e];
        float4 v = *(const float4*)(UW + (size_t)s * 512 + l * 4);
        m.x = fmaxf(m.x, v.x); m.y = fmaxf(m.y, v.y);
        m.z = fmaxf(m.z, v.z); m.w = fmaxf(m.w, v.w);
    }
    float4 w = *(const float4*)(UW + (size_t)i * 512 + 256 + l * 4);
    float4 r;
    // empty segment: m = -3.4e38 -> m+w < 0 -> relu gives 0 (PyG fill). safe.
    r.x = fmaxf(m.x + w.x, 0.0f);
    r.y = fmaxf(m.y + w.y, 0.0f);
    r.z = fmaxf(m.z + w.z, 0.0f);
    r.w = fmaxf(m.w + w.w, 0.0f);
    *(float4*)(out + (size_t)i * OSTR + ooff + l * 4) = r;
}

extern "C" void kernel_launch(void* const* d_in, const int* in_sizes, int n_in,
                              void* d_out, int out_size, void* d_ws, size_t ws_size,
                              hipStream_t stream) {
    const float* x0 = (const float*)d_in[0];
    const int* ei = (const int*)d_in[1];
    const int* srcIdx = ei;          // edge_index[0]
    const int* dstIdx = ei + EDGES;  // edge_index[1]
    float* out = (float*)d_out;

    // ws layout (9.5 MB):
    char* w = (char*)d_ws;
    float* UW = (float*)w;                                   // 4096*512 fp32 = 8 MB
    short* Wp = (short*)(w + 8388608);                       // 3*512*256 bf16 = 768 KB
    int* offsets = (int*)(w + 8388608 + 786432);             // 4097 ints
    int* cnt = (int*)(w + 8388608 + 786432 + 16512);         // 4096 ints (hist+cursor)
    int* srcS = (int*)(w + 8388608 + 786432 + 16512 + 16384);// 65536 ints

    k_init<<<NODES, 256, 0, stream>>>(x0, out);
    k_wprep<<<3 * 512, 256, 0, stream>>>((const float*)d_in[2], (const float*)d_in[4],
                                         (const float*)d_in[6], Wp);
    k_zero<<<16, 256, 0, stream>>>(cnt);
    k_hist<<<EDGES / 256, 256, 0, stream>>>(dstIdx, cnt);
    k_scan<<<1, 256, 0, stream>>>(cnt, offsets);
    k_scatter<<<EDGES / 256, 256, 0, stream>>>(srcIdx, dstIdx, offsets, cnt, srcS);

    for (int l = 0; l < 3; ++l) {
        k_gemm<<<dim3(NODES / 32, 2), 256, 0, stream>>>(out + l * 256, Wp + l * 131072,
                                                        (const float*)d_in[3 + 2 * l], UW);
        k_edge<<<NODES, 64, 0, stream>>>(UW, offsets, srcS, out, (l + 1) * 256);
    }
}

// Round 4
// 145.683 us; speedup vs baseline: 2.1433x; 1.0560x over previous
//
#include <hip/hip_runtime.h>
#include <hip/hip_bf16.h>

// GNN EdgeConv, 3 layers, fp32 in/out.
// msg_e = relu(u[src]+w[dst]);  u = x@Wa^T (bf16 table), w = x@(Wb-Wa)^T + b (fp32).
// dst-sorted edges (counting sort) -> per-node gather-max, zero atomics.
// Round-4: u-table in bf16 (halves k_edge gather bytes, 2MB L2-resident),
// bf16 xbuf mirror feeds GEMM A-staging, setup kernels fused.

#define NODES 4096
#define EDGES 65536
#define OSTR 1024   // out row stride (fp32)

typedef __attribute__((ext_vector_type(8))) short bf16x8;
typedef __attribute__((ext_vector_type(4))) float f32x4;

__device__ __forceinline__ unsigned short f2bf(float f) {
    unsigned int x = __float_as_uint(f);
    return (unsigned short)((x + 0x7fff + ((x >> 16) & 1)) >> 16); // RNE
}
__device__ __forceinline__ float bf2f(unsigned short u) {
    return __uint_as_float(((unsigned int)u) << 16);
}

// ---- fused setup: [0,4096) x0->out+xbuf | [4096,5632) wprep | [5632,5648) zero cnt
__global__ __launch_bounds__(256) void k_setup(const float* __restrict__ x0,
                                               float* __restrict__ out,
                                               unsigned short* __restrict__ xbuf,
                                               const float* __restrict__ W0,
                                               const float* __restrict__ W1,
                                               const float* __restrict__ W2,
                                               short* __restrict__ Wp,
                                               int* __restrict__ cnt) {
    int b = blockIdx.x, t = threadIdx.x;
    if (b < NODES) {
        int idx = b * 256 + t;
        float v = x0[idx];
        out[b * OSTR + (idx & 255)] = v;
        xbuf[idx] = f2bf(v);
    } else if (b < NODES + 1536) {
        int b2 = b - NODES;
        int layer = b2 >> 9;                       // 512 blocks/layer
        int idx = (b2 & 511) * 256 + t;            // 0 .. 512*256-1
        const float* W = layer == 0 ? W0 : (layer == 1 ? W1 : W2);
        int n = idx >> 8, c = idx & 255;
        float v;
        if (n < 256) v = W[n * 512 + c];                                   // Wa[n][c]
        else         v = W[(n - 256) * 512 + 256 + c] - W[(n - 256) * 512 + c]; // (Wb-Wa)
        Wp[layer * 131072 + idx] = (short)f2bf(v);
    } else {
        cnt[(b - NODES - 1536) * 256 + t] = 0;
    }
}

// ---- counting sort of edges by dst ----
__global__ __launch_bounds__(256) void k_hist(const int* __restrict__ dst,
                                              int* __restrict__ cnt) {
    int e = blockIdx.x * 256 + threadIdx.x;
    atomicAdd(&cnt[dst[e]], 1);
}
// single block: exclusive scan cnt[4096] -> offsets[4097]; re-zero cnt (cursor).
__global__ __launch_bounds__(256) void k_scan(int* __restrict__ cnt,
                                              int* __restrict__ offsets) {
    __shared__ int part[256];
    int t = threadIdx.x, base = t * 16;
    int loc[16], s = 0;
#pragma unroll
    for (int j = 0; j < 16; ++j) { loc[j] = cnt[base + j]; s += loc[j]; }
    part[t] = s;
    __syncthreads();
    for (int d = 1; d < 256; d <<= 1) {
        int v = (t >= d) ? part[t - d] : 0;
        __syncthreads();
        part[t] += v;
        __syncthreads();
    }
    int run = part[t] - s;  // exclusive prefix
#pragma unroll
    for (int j = 0; j < 16; ++j) { offsets[base + j] = run; run += loc[j]; cnt[base + j] = 0; }
    if (t == 255) offsets[4096] = run;
}
__global__ __launch_bounds__(256) void k_scatter(const int* __restrict__ src,
                                                 const int* __restrict__ dst,
                                                 const int* __restrict__ offsets,
                                                 int* __restrict__ cursor,
                                                 int* __restrict__ srcS) {
    int e = blockIdx.x * 256 + threadIdx.x;
    int d = dst[e];
    int p = offsets[d] + atomicAdd(&cursor[d], 1);
    srcS[p] = src[e];
}

// ---- node GEMM: u=X@Wa^T -> UWu bf16 [4096][256]; w=X@(Wb-Wa)^T+b -> UWw fp32.
// A from bf16 xbuf. Block: 32 rows x 256 cols; grid (128, 2=nhalf). 4 waves.
__global__ __launch_bounds__(256) void k_gemm(const unsigned short* __restrict__ xbuf, // [4096][256] bf16
                                              const short* __restrict__ Wp,            // [512][256] bf16
                                              const float* __restrict__ bias,          // [256] fp32
                                              unsigned short* __restrict__ UWu,        // [4096][256] bf16
                                              float* __restrict__ UWw) {               // [4096][256] fp32
    // stride 264 shorts = 132 dwords == 4 mod 32 -> 2-way LDS conflicts (free, m136)
    __shared__ __align__(16) short Alds[32 * 264];

    const int t = threadIdx.x;
    const int m0 = blockIdx.x * 32;
    const int nhalf = blockIdx.y;

    // stage A: 32 rows x 256 k bf16 (512 B/row); 8 threads/row x 4 16B-chunks
    {
        int r = t >> 3, ch = t & 7;
        const int4* ps = (const int4*)(xbuf + (size_t)(m0 + r) * 256);
        short* arow = &Alds[r * 264];
#pragma unroll
        for (int j = 0; j < 4; ++j) {
            int c = ch + 8 * j;                  // 16B chunk, 0..31
            *(int4*)(arow + c * 8) = ps[c];
        }
    }
    __syncthreads();

    const int wave = t >> 6, lane = t & 63;
    const int lm = lane & 15, kq = lane >> 4;
    const int nbl = wave * 64;                   // local col base in [0,256)
    const int nb = nhalf * 256 + nbl;            // row of Wp

    f32x4 acc[2][4];
#pragma unroll
    for (int mt = 0; mt < 2; ++mt)
#pragma unroll
        for (int nt = 0; nt < 4; ++nt) acc[mt][nt] = (f32x4){0.f, 0.f, 0.f, 0.f};

    // A-frag: A[m=lane&15][k=(lane>>4)*8+j]; B-frag: B[k][n=lane&15] = Wp row n
    const short* a0p = &Alds[lm * 264 + kq * 8];
    const short* a1p = a0p + 16 * 264;
    const short* bp = Wp + (size_t)(nb + lm) * 256 + kq * 8;

#pragma unroll
    for (int ks = 0; ks < 8; ++ks) {
        const int ko = ks * 32;
        bf16x8 a0 = *(const bf16x8*)(a0p + ko);
        bf16x8 a1 = *(const bf16x8*)(a1p + ko);
        bf16x8 b0 = *(const bf16x8*)(bp + ko);
        bf16x8 b1 = *(const bf16x8*)(bp + 16 * 256 + ko);
        bf16x8 b2 = *(const bf16x8*)(bp + 32 * 256 + ko);
        bf16x8 b3 = *(const bf16x8*)(bp + 48 * 256 + ko);
        acc[0][0] = __builtin_amdgcn_mfma_f32_16x16x32_bf16(a0, b0, acc[0][0], 0, 0, 0);
        acc[0][1] = __builtin_amdgcn_mfma_f32_16x16x32_bf16(a0, b1, acc[0][1], 0, 0, 0);
        acc[0][2] = __builtin_amdgcn_mfma_f32_16x16x32_bf16(a0, b2, acc[0][2], 0, 0, 0);
        acc[0][3] = __builtin_amdgcn_mfma_f32_16x16x32_bf16(a0, b3, acc[0][3], 0, 0, 0);
        acc[1][0] = __builtin_amdgcn_mfma_f32_16x16x32_bf16(a1, b0, acc[1][0], 0, 0, 0);
        acc[1][1] = __builtin_amdgcn_mfma_f32_16x16x32_bf16(a1, b1, acc[1][1], 0, 0, 0);
        acc[1][2] = __builtin_amdgcn_mfma_f32_16x16x32_bf16(a1, b2, acc[1][2], 0, 0, 0);
        acc[1][3] = __builtin_amdgcn_mfma_f32_16x16x32_bf16(a1, b3, acc[1][3], 0, 0, 0);
    }

    // epilogue: C/D col=lane&15, row=(lane>>4)*4+reg (m89/m91)
#pragma unroll
    for (int nt = 0; nt < 4; ++nt) {
        int nc = nbl + nt * 16 + lm;             // local col 0..255
        float bc = (nhalf == 1) ? bias[nc] : 0.0f;
#pragma unroll
        for (int mt = 0; mt < 2; ++mt) {
#pragma unroll
            for (int p = 0; p < 4; ++p) {
                int erow = mt * 16 + kq * 4 + p;
                float v = acc[mt][nt][p] + bc;
                size_t off = (size_t)(m0 + erow) * 256 + nc;
                if (nhalf == 0) UWu[off] = f2bf(v);
                else            UWw[off] = v;
            }
        }
    }
}

// ---- per-dst gather-max: out[i] = relu(max_e u[src]+w[i]); empty->0.
// 256 threads = 4 nodes/block, 1 wave/node; u gathers are bf16 (8 B/lane).
__global__ __launch_bounds__(256) void k_edge(const unsigned short* __restrict__ UWu,
                                              const float* __restrict__ UWw,
                                              const int* __restrict__ offsets,
                                              const int* __restrict__ srcS,
                                              float* __restrict__ out,
                                              unsigned short* __restrict__ xbuf,
                                              int ooff) {
    const int i = blockIdx.x * 4 + (threadIdx.x >> 6);
    const int l = threadIdx.x & 63;
    const int beg = offsets[i], end = offsets[i + 1];

    const float NEG = -3.4e38f;
    float m0 = NEG, m1 = NEG, m2 = NEG, m3 = NEG;
    int e = beg;
    for (; e + 4 <= end; e += 4) {
        int s0 = srcS[e], s1 = srcS[e + 1], s2 = srcS[e + 2], s3 = srcS[e + 3];
        ushort4 v0 = *(const ushort4*)(UWu + (size_t)s0 * 256 + l * 4);
        ushort4 v1 = *(const ushort4*)(UWu + (size_t)s1 * 256 + l * 4);
        ushort4 v2 = *(const ushort4*)(UWu + (size_t)s2 * 256 + l * 4);
        ushort4 v3 = *(const ushort4*)(UWu + (size_t)s3 * 256 + l * 4);
        m0 = fmaxf(fmaxf(fmaxf(m0, bf2f(v0.x)), fmaxf(bf2f(v1.x), bf2f(v2.x))), bf2f(v3.x));
        m1 = fmaxf(fmaxf(fmaxf(m1, bf2f(v0.y)), fmaxf(bf2f(v1.y), bf2f(v2.y))), bf2f(v3.y));
        m2 = fmaxf(fmaxf(fmaxf(m2, bf2f(v0.z)), fmaxf(bf2f(v1.z), bf2f(v2.z))), bf2f(v3.z));
        m3 = fmaxf(fmaxf(fmaxf(m3, bf2f(v0.w)), fmaxf(bf2f(v1.w), bf2f(v2.w))), bf2f(v3.w));
    }
    for (; e < end; ++e) {
        int s = srcS[e];
        ushort4 v = *(const ushort4*)(UWu + (size_t)s * 256 + l * 4);
        m0 = fmaxf(m0, bf2f(v.x)); m1 = fmaxf(m1, bf2f(v.y));
        m2 = fmaxf(m2, bf2f(v.z)); m3 = fmaxf(m3, bf2f(v.w));
    }
    float4 w = *(const float4*)(UWw + (size_t)i * 256 + l * 4);
    float4 r;
    // empty segment: m=-3.4e38 -> m+w<0 -> relu 0 (PyG fill semantics)
    r.x = fmaxf(m0 + w.x, 0.0f);
    r.y = fmaxf(m1 + w.y, 0.0f);
    r.z = fmaxf(m2 + w.z, 0.0f);
    r.w = fmaxf(m3 + w.w, 0.0f);
    *(float4*)(out + (size_t)i * OSTR + ooff + l * 4) = r;
    ushort4 rb;
    rb.x = f2bf(r.x); rb.y = f2bf(r.y); rb.z = f2bf(r.z); rb.w = f2bf(r.w);
    *(ushort4*)(xbuf + (size_t)i * 256 + l * 4) = rb;
}

extern "C" void kernel_launch(void* const* d_in, const int* in_sizes, int n_in,
                              void* d_out, int out_size, void* d_ws, size_t ws_size,
                              hipStream_t stream) {
    const float* x0 = (const float*)d_in[0];
    const int* ei = (const int*)d_in[1];
    const int* srcIdx = ei;          // edge_index[0]
    const int* dstIdx = ei + EDGES;  // edge_index[1]
    float* out = (float*)d_out;

    // ws layout (~9.3 MB):
    char* w = (char*)d_ws;
    unsigned short* UWu = (unsigned short*)w;                 // 2 MB bf16 [4096][256]
    float* UWw = (float*)(w + 2097152);                       // 4 MB fp32 [4096][256]
    unsigned short* xbuf = (unsigned short*)(w + 6291456);    // 2 MB bf16 [4096][256]
    short* Wp = (short*)(w + 8388608);                        // 768 KB bf16 3x[512][256]
    int* offsets = (int*)(w + 9175040);                       // 4097 ints
    int* cnt = (int*)(w + 9191552);                           // 4096 ints
    int* srcS = (int*)(w + 9207936);                          // 65536 ints

    k_setup<<<NODES + 1536 + 16, 256, 0, stream>>>(x0, out, xbuf,
                                                   (const float*)d_in[2], (const float*)d_in[4],
                                                   (const float*)d_in[6], Wp, cnt);
    k_hist<<<EDGES / 256, 256, 0, stream>>>(dstIdx, cnt);
    k_scan<<<1, 256, 0, stream>>>(cnt, offsets);
    k_scatter<<<EDGES / 256, 256, 0, stream>>>(srcIdx, dstIdx, offsets, cnt, srcS);

    for (int l = 0; l < 3; ++l) {
        k_gemm<<<dim3(NODES / 32, 2), 256, 0, stream>>>(xbuf, Wp + l * 131072,
                                                        (const float*)d_in[3 + 2 * l],
                                                        UWu, UWw);
        k_edge<<<NODES / 4, 256, 0, stream>>>(UWu, UWw, offsets, srcS, out, xbuf,
                                              (l + 1) * 256);
    }
}